// Round 7
// baseline (645.120 us; speedup 1.0000x reference)
//
#include <hip/hip_runtime.h>
#include <hip/hip_bf16.h>
#include <hip/hip_fp16.h>

// Problem constants (reference: OUT=11008, IN=4096, B=2, S=2048)
#define K_DIM 4096
#define N_DIM 11008
#define M_DIM 4096  // B*S

typedef _Float16 f16x8 __attribute__((ext_vector_type(8)));
typedef float f32x16 __attribute__((ext_vector_type(16)));

typedef const __attribute__((address_space(1))) void* gas_cptr;
typedef __attribute__((address_space(3))) void* las_ptr;

__device__ __forceinline__ void gload_lds16(const void* g, void* l) {
  // async global->LDS, 16B per lane; LDS dest = wave-uniform base + lane*16
  __builtin_amdgcn_global_load_lds((gas_cptr)g, (las_ptr)l, 16, 0, 0);
}

// ---------------------------------------------------------------------------
// Dequant: W_recon[o][i] = sign * scale * (alpha*Xn + (1-alpha)*Xn^p),
//          Xn = mag / divisor.  8 elements per thread, fp16 output [N][K].
// ---------------------------------------------------------------------------
__global__ __launch_bounds__(256) void dequant_kernel(
    const int* __restrict__ mag, const int* __restrict__ sgn,
    const float* __restrict__ scales, const float* __restrict__ alphas,
    const float* __restrict__ powers, const float* __restrict__ divisors,
    _Float16* __restrict__ Wh) {
  const int VPR = K_DIM / 8;  // 512 vec8 per row
  int v = blockIdx.x * 256 + threadIdx.x;  // grid exactly covers N*K/8
  int o = v / VPR;
  int base = o * K_DIM + (v - o * VPR) * 8;

  int4 m0 = *(const int4*)(mag + base);
  int4 m1 = *(const int4*)(mag + base + 4);
  int4 s0 = *(const int4*)(sgn + base);
  int4 s1 = *(const int4*)(sgn + base + 4);

  float sc = scales[o];
  float al = alphas[o];
  float p  = powers[o];
  float idv = 1.0f / divisors[o];

  int mi[8] = {m0.x, m0.y, m0.z, m0.w, m1.x, m1.y, m1.z, m1.w};
  int si[8] = {s0.x, s0.y, s0.z, s0.w, s1.x, s1.y, s1.z, s1.w};

  f16x8 out;
#pragma unroll
  for (int e = 0; e < 8; ++e) {
    float xn = (float)mi[e] * idv;
    float pw = __powf(xn, p);          // xn==0 -> 0 (exp(-inf))
    float cur = al * xn + (1.0f - al) * pw;
    float w = (float)si[e] * (cur * sc);
    out[e] = (_Float16)w;
  }
  *(f16x8*)&Wh[base] = out;
}

// ---------------------------------------------------------------------------
// x (fp32) -> fp16, 8 elements per thread
// ---------------------------------------------------------------------------
__global__ __launch_bounds__(256) void xconv_kernel(const float* __restrict__ x,
                                                    _Float16* __restrict__ xh) {
  int v = blockIdx.x * 256 + threadIdx.x;
  int base = v * 8;
  float4 a = *(const float4*)(x + base);
  float4 b = *(const float4*)(x + base + 4);
  f16x8 o;
  o[0] = (_Float16)a.x; o[1] = (_Float16)a.y;
  o[2] = (_Float16)a.z; o[3] = (_Float16)a.w;
  o[4] = (_Float16)b.x; o[5] = (_Float16)b.y;
  o[6] = (_Float16)b.z; o[7] = (_Float16)b.w;
  *(f16x8*)&xh[base] = o;
}

// ---------------------------------------------------------------------------
// 256x256 GEMM_BT, round-4 schedule, MFMA shape = 32x32x16 (2495 TF ceiling
// vs 2075 for 16x16x32).  BK=64, 512 threads = 8 waves (2x4), wave tile
// 128x64 = 4 m-frags x 2 n-frags of 32x32.
// LDS: 2 dbuf x 4 regions (A-kh0, A-kh1, B-kh0, B-kh1), 16KB each = 128 KiB.
// Swizzle (T2, verified 0 conflicts round 4/6): colbyte ^= ((row>>1)&3)<<4;
// still bijective per 8-lane b128 phase with the 32x32 frag pattern
// (row = lane&31, kgrp = lane>>5).
// Schedule (= round 4, 378us best): per-phase staging, vmcnt(4) at ph2/ph4.
// ---------------------------------------------------------------------------
#define BM 256
#define BN 256
#define BK 64
#define NT (K_DIM / BK)   // 64 K-tiles
#define NBN (N_DIM / BN)  // 43
#define NBM (M_DIM / BM)  // 16

#define BAR() __builtin_amdgcn_s_barrier()
#define LGKM0()                                          \
  asm volatile("s_waitcnt lgkmcnt(0)" ::: "memory");     \
  __builtin_amdgcn_sched_barrier(0)
#define VMC(N) asm volatile("s_waitcnt vmcnt(" #N ")" ::: "memory")

// stage one k-half region: 2 gloads/thread (j=0: rows 0-127, j=1: rows 128-255)
#define STAGE(buf_, reg_, gbase_)                                        \
  do {                                                                   \
    gload_lds16((gbase_), &lds[buf_][reg_][wave * 512]);                 \
    gload_lds16((gbase_) + 128 * (size_t)K_DIM,                          \
                &lds[buf_][reg_][4096 + wave * 512]);                    \
  } while (0)

// A-frags for m-half qm: af[lm][ks], row base = wm*128 + qm*64 + lm*32
#define LOAD_A4(buf_, kh_, qm_)                                          \
  do {                                                                   \
    const _Float16* rgn = &lds[buf_][kh_][0];                            \
    af[0][0] = *(const f16x8*)&rgn[abase + ((qm_)*64 + 0) * 32 + fo0];   \
    af[0][1] = *(const f16x8*)&rgn[abase + ((qm_)*64 + 0) * 32 + fo1];   \
    af[1][0] = *(const f16x8*)&rgn[abase + ((qm_)*64 + 32) * 32 + fo0];  \
    af[1][1] = *(const f16x8*)&rgn[abase + ((qm_)*64 + 32) * 32 + fo1];  \
  } while (0)

// B-frags: bf[nf][ks], col base = wn*64 + nf*32
#define LOAD_B4(buf_, kh_)                                               \
  do {                                                                   \
    const _Float16* rgn = &lds[buf_][2 + (kh_)][0];                      \
    bf[0][0] = *(const f16x8*)&rgn[bbase + 0 + fo0];                     \
    bf[0][1] = *(const f16x8*)&rgn[bbase + 0 + fo1];                     \
    bf[1][0] = *(const f16x8*)&rgn[bbase + 1024 + fo0];                  \
    bf[1][1] = *(const f16x8*)&rgn[bbase + 1024 + fo1];                  \
  } while (0)

// 8 x mfma_32x32x16 per phase; ks outer so dependent acc-pairs are 4 apart
#define MFMA_Q(qm_)                                                      \
  do {                                                                   \
    __builtin_amdgcn_s_setprio(1);                                       \
    _Pragma("unroll") for (int ks = 0; ks < 2; ++ks)                     \
        _Pragma("unroll") for (int lm = 0; lm < 2; ++lm)                 \
            _Pragma("unroll") for (int nf = 0; nf < 2; ++nf)             \
                acc[(qm_)*2 + lm][nf] =                                  \
                    __builtin_amdgcn_mfma_f32_32x32x16_f16(              \
                        af[lm][ks], bf[nf][ks], acc[(qm_)*2 + lm][nf],   \
                        0, 0, 0);                                        \
    __builtin_amdgcn_s_setprio(0);                                       \
  } while (0)

__global__ __launch_bounds__(512, 2) void gemm_kernel(
    const _Float16* __restrict__ A, const _Float16* __restrict__ Bt,
    float* __restrict__ C) {
  __shared__ _Float16 lds[2][4][8192];  // 128 KiB

  const int tid = threadIdx.x;
  const int lane = tid & 63;
  const int wave = tid >> 6;
  const int wm = wave >> 2;  // 0..1
  const int wn = wave & 3;   // 0..3

  // XCD-aware swizzle (T1), bn-fastest (round-4 proven): 688 = 8 XCDs x 86
  const int bid = blockIdx.x;
  const int g = (bid & 7) * 86 + (bid >> 3);
  const int bm = g / NBN;
  const int bn = g - bm * NBN;
  const size_t row0 = (size_t)bm * BM;
  const size_t col0 = (size_t)bn * BN;

  // ---- staging addressing: region byte P = j*8192 + tid*16 -> row/colbyte
  const int sr = tid >> 2;               // row within j=0 half
  const int pcb = (tid & 3) * 16;        // physical col byte
  const int cb = pcb ^ (((sr >> 1) & 3) << 4);  // logical col byte (T2 swizzle)
  const _Float16* gA = A + (row0 + sr) * (size_t)K_DIM + cb / 2;
  const _Float16* gB = Bt + (col0 + sr) * (size_t)K_DIM + cb / 2;

  // ---- fragment read addressing (32x32x16: row = lane&31, kgrp = lane>>5)
  const int frow = lane & 31;
  const int kgrp = lane >> 5;
  const int swz = ((lane >> 1) & 3) << 4;  // = ((frow>>1)&3)<<4
  const int fo0 = ((0 * 32 + kgrp * 16) ^ swz) / 2;  // ks=0 f16 offset
  const int fo1 = ((1 * 32 + kgrp * 16) ^ swz) / 2;  // ks=1 f16 offset
  const int abase = (wm * 128 + frow) * 32;
  const int bbase = (wn * 64 + frow) * 32;

  f32x16 acc[4][2];
#pragma unroll
  for (int m = 0; m < 4; ++m)
#pragma unroll
    for (int n = 0; n < 2; ++n) acc[m][n] = (f32x16)0.0f;

  // ---- prologue: stage all 4 halves of tile 0 into buf 0
  STAGE(0, 0, gA);        // A kh0
  STAGE(0, 2, gB);        // B kh0
  STAGE(0, 1, gA + 32);   // A kh1
  STAGE(0, 3, gB + 32);   // B kh1
  VMC(4);                 // A kh0 + B kh0 resident
  BAR();

  f16x8 af[2][2], bf[2][2];

  for (int t = 0; t < NT - 1; ++t) {
    const int cur = t & 1;
    const int nxt = cur ^ 1;
    const _Float16* gAn = gA + (size_t)(t + 1) * BK;
    const _Float16* gBn = gB + (size_t)(t + 1) * BK;

    // Phase 1: kh0, m-half0 | stage A-kh0(t+1)
    LOAD_A4(cur, 0, 0);
    LOAD_B4(cur, 0);
    STAGE(nxt, 0, gAn);
    BAR(); LGKM0();
    MFMA_Q(0);
    BAR();
    // Phase 2: kh0, m-half1 | stage B-kh0(t+1) | vmcnt(4): A1,B1(t) resident
    LOAD_A4(cur, 0, 1);
    STAGE(nxt, 2, gBn);
    VMC(4);
    BAR(); LGKM0();
    MFMA_Q(1);
    BAR();
    // Phase 3: kh1, m-half0 | stage A-kh1(t+1)
    LOAD_A4(cur, 1, 0);
    LOAD_B4(cur, 1);
    STAGE(nxt, 1, gAn + 32);
    BAR(); LGKM0();
    MFMA_Q(0);
    BAR();
    // Phase 4: kh1, m-half1 | stage B-kh1(t+1) | vmcnt(4): A0,B0(t+1) resident
    LOAD_A4(cur, 1, 1);
    STAGE(nxt, 3, gBn + 32);
    VMC(4);
    BAR(); LGKM0();
    MFMA_Q(1);
    BAR();
  }

  // ---- tail: tile NT-1 in buf 1, no staging
  LOAD_A4(1, 0, 0);
  LOAD_B4(1, 0);
  BAR(); LGKM0();
  MFMA_Q(0);
  BAR();
  LOAD_A4(1, 0, 1);
  VMC(0);  // A-kh1, B-kh1 of last tile fully resident
  BAR(); LGKM0();
  MFMA_Q(1);
  BAR();
  LOAD_A4(1, 1, 0);
  LOAD_B4(1, 1);
  BAR(); LGKM0();
  MFMA_Q(0);
  BAR();
  LOAD_A4(1, 1, 1);
  LGKM0();
  MFMA_Q(1);

  // ---- epilogue: 32x32 C/D layout col=lane&31,
  //      row=(reg&3)+8*(reg>>2)+4*(lane>>5)  (m74/m101-verified)
  const int ccol = lane & 31;
  const int rbase = 4 * (lane >> 5);
#pragma unroll
  for (int mf = 0; mf < 4; ++mf) {
#pragma unroll
    for (int nf = 0; nf < 2; ++nf) {
#pragma unroll
      for (int reg = 0; reg < 16; ++reg) {
        int row = (int)row0 + wm * 128 + mf * 32 + (reg & 3) + 8 * (reg >> 2) + rbase;
        int col = (int)col0 + wn * 64 + nf * 32 + ccol;
        C[(size_t)row * N_DIM + col] = acc[mf][nf][reg];
      }
    }
  }
}

// ---------------------------------------------------------------------------
extern "C" void kernel_launch(void* const* d_in, const int* in_sizes, int n_in,
                              void* d_out, int out_size, void* d_ws, size_t ws_size,
                              hipStream_t stream) {
  const float* x = (const float*)d_in[0];
  const int* Wmag = (const int*)d_in[1];
  const int* Wsgn = (const int*)d_in[2];
  const float* scales = (const float*)d_in[3];
  const float* alphas = (const float*)d_in[4];
  const float* powers = (const float*)d_in[5];
  const float* divisors = (const float*)d_in[6];
  float* out = (float*)d_out;

  _Float16* xh = (_Float16*)d_ws;                        // 32 MB
  _Float16* Wh = xh + (size_t)M_DIM * K_DIM;             // 90 MB

  // 1) dequantize W -> fp16 [N][K]
  {
    int nthreads_total = (N_DIM * K_DIM) / 8;  // 5,636,096
    dequant_kernel<<<nthreads_total / 256, 256, 0, stream>>>(
        Wmag, Wsgn, scales, alphas, powers, divisors, Wh);
  }
  // 2) x -> fp16 [M][K]
  {
    int nthreads_total = (M_DIM * K_DIM) / 8;  // 2,097,152
    xconv_kernel<<<nthreads_total / 256, 256, 0, stream>>>(x, xh);
  }
  // 3) GEMM: [M][K] x [N][K]^T -> [M][N] f32
  {
    dim3 grid(NBM * NBN);  // 16*43 = 688
    gemm_kernel<<<grid, 512, 0, stream>>>(xh, Wh, out);
  }
}

// Round 8
// 588.347 us; speedup vs baseline: 1.0965x; 1.0965x over previous
//
#include <hip/hip_runtime.h>
#include <hip/hip_bf16.h>
#include <hip/hip_fp16.h>

// Problem constants (reference: OUT=11008, IN=4096, B=2, S=2048)
#define K_DIM 4096
#define N_DIM 11008
#define M_DIM 4096  // B*S

typedef _Float16 f16x8 __attribute__((ext_vector_type(8)));
typedef float f32x4 __attribute__((ext_vector_type(4)));

typedef const __attribute__((address_space(1))) void* gas_cptr;
typedef __attribute__((address_space(3))) void* las_ptr;

__device__ __forceinline__ void gload_lds16(const void* g, void* l) {
  __builtin_amdgcn_global_load_lds((gas_cptr)g, (las_ptr)l, 16, 0, 0);
}

// ---------------------------------------------------------------------------
// Dequant: W_recon[o][i] = sign * scale * (alpha*Xn + (1-alpha)*Xn^p)
// ---------------------------------------------------------------------------
__global__ __launch_bounds__(256) void dequant_kernel(
    const int* __restrict__ mag, const int* __restrict__ sgn,
    const float* __restrict__ scales, const float* __restrict__ alphas,
    const float* __restrict__ powers, const float* __restrict__ divisors,
    _Float16* __restrict__ Wh) {
  const int VPR = K_DIM / 8;
  int v = blockIdx.x * 256 + threadIdx.x;
  int o = v / VPR;
  int base = o * K_DIM + (v - o * VPR) * 8;

  int4 m0 = *(const int4*)(mag + base);
  int4 m1 = *(const int4*)(mag + base + 4);
  int4 s0 = *(const int4*)(sgn + base);
  int4 s1 = *(const int4*)(sgn + base + 4);

  float sc = scales[o];
  float al = alphas[o];
  float p  = powers[o];
  float idv = 1.0f / divisors[o];

  int mi[8] = {m0.x, m0.y, m0.z, m0.w, m1.x, m1.y, m1.z, m1.w};
  int si[8] = {s0.x, s0.y, s0.z, s0.w, s1.x, s1.y, s1.z, s1.w};

  f16x8 out;
#pragma unroll
  for (int e = 0; e < 8; ++e) {
    float xn = (float)mi[e] * idv;
    float pw = __powf(xn, p);
    float cur = al * xn + (1.0f - al) * pw;
    float w = (float)si[e] * (cur * sc);
    out[e] = (_Float16)w;
  }
  *(f16x8*)&Wh[base] = out;
}

// ---------------------------------------------------------------------------
// x (fp32) -> fp16
// ---------------------------------------------------------------------------
__global__ __launch_bounds__(256) void xconv_kernel(const float* __restrict__ x,
                                                    _Float16* __restrict__ xh) {
  int v = blockIdx.x * 256 + threadIdx.x;
  int base = v * 8;
  float4 a = *(const float4*)(x + base);
  float4 b = *(const float4*)(x + base + 4);
  f16x8 o;
  o[0] = (_Float16)a.x; o[1] = (_Float16)a.y;
  o[2] = (_Float16)a.z; o[3] = (_Float16)a.w;
  o[4] = (_Float16)b.x; o[5] = (_Float16)b.y;
  o[6] = (_Float16)b.z; o[7] = (_Float16)b.w;
  *(f16x8*)&xh[base] = o;
}

// ---------------------------------------------------------------------------
// 256x256 GEMM_BT, BK=64, 512 thr = 8 waves (2x4), 16x16x32 f16 MFMA.
// ONE barrier + ONE vmcnt per K-tile; within a tile the 4 phases are
// register-pipelined: each phase issues the NEXT phase's ds_reads before its
// own MFMA burst, gated by counted lgkmcnt (DS retires in-order per wave).
// This overlaps the LDS pipe (~580cy/phase/CU) with the MFMA pipe
// (~620cy/phase/CU) -> max instead of sum (round-7 diagnosis).
// Hazards: cur/nxt LDS buffers disjoint; every ds_read is lgkm-waited before
// the tile-end barrier, so staging over nxt is WAR-safe; VMC(0)-before-BAR
// publishes all waves' staged data; prefetch distance = 1 tile (~2500cy).
// Swizzle (T2, 0 conflicts proven r4/r6): colbyte ^= ((row>>1)&3)<<4.
// ---------------------------------------------------------------------------
#define BM 256
#define BN 256
#define BK 64
#define NT (K_DIM / BK)   // 64
#define NBN (N_DIM / BN)  // 43
#define NBM (M_DIM / BM)  // 16

#define BAR() __builtin_amdgcn_s_barrier()
#define SBAR() __builtin_amdgcn_sched_barrier(0)
#define LGKMC(N)                                              \
  asm volatile("s_waitcnt lgkmcnt(" #N ")" ::: "memory");     \
  __builtin_amdgcn_sched_barrier(0)
#define VMC(N) asm volatile("s_waitcnt vmcnt(" #N ")" ::: "memory")

#define STAGE(buf_, reg_, gbase_)                                        \
  do {                                                                   \
    gload_lds16((gbase_), &lds[buf_][reg_][wave * 512]);                 \
    gload_lds16((gbase_) + 128 * (size_t)K_DIM,                          \
                &lds[buf_][reg_][4096 + wave * 512]);                    \
  } while (0)

// A-frags (4 x b128) for m-half qm of k-half kh into dst_[0..3]
#define RD_A(dst_, buf_, kh_, qm_)                                       \
  _Pragma("unroll") for (int m = 0; m < 4; ++m)                          \
      dst_[m] = *(const f16x8*)&lds[buf_][kh_][aoff + ((qm_)*4 + m) * 512];

// B-frags (4 x b128) for k-half kh into dst_[0..3]
#define RD_B(dst_, buf_, kh_)                                            \
  _Pragma("unroll") for (int n = 0; n < 4; ++n)                          \
      dst_[n] = *(const f16x8*)&lds[buf_][2 + (kh_)][boff + n * 512];

#define MFMA16(a_, b_, qm_)                                              \
  do {                                                                   \
    __builtin_amdgcn_s_setprio(1);                                       \
    _Pragma("unroll") for (int i = 0; i < 4; ++i)                        \
        _Pragma("unroll") for (int j = 0; j < 4; ++j)                    \
            acc[(qm_)*4 + i][j] = __builtin_amdgcn_mfma_f32_16x16x32_f16(\
                a_[i], b_[j], acc[(qm_)*4 + i][j], 0, 0, 0);             \
    __builtin_amdgcn_s_setprio(0);                                       \
  } while (0)

// One K-tile: preload ph1, then pipelined phases. STAGE_OPT staging of t+1.
#define TILE_BODY(buf_, DO_STAGE_)                                       \
  do {                                                                   \
    VMC(0);                                                              \
    BAR();                                                               \
    DO_STAGE_;                                                           \
    RD_A(aX, buf_, 0, 0);                                                \
    RD_B(bX, buf_, 0);                                                   \
    LGKMC(0);                                                            \
    /* ph1 */                                                            \
    RD_A(aY, buf_, 0, 1);                                                \
    SBAR();                                                              \
    MFMA16(aX, bX, 0);                                                   \
    /* ph2 */                                                            \
    RD_A(aX, buf_, 1, 0);                                                \
    RD_B(bY, buf_, 1);                                                   \
    SBAR();                                                              \
    LGKMC(8);                                                            \
    MFMA16(aY, bX, 1);                                                   \
    /* ph3 */                                                            \
    RD_A(aY, buf_, 1, 1);                                                \
    SBAR();                                                              \
    LGKMC(4);                                                            \
    MFMA16(aX, bY, 0);                                                   \
    /* ph4 */                                                            \
    LGKMC(0);                                                            \
    MFMA16(aY, bY, 1);                                                   \
  } while (0)

__global__ __launch_bounds__(512, 2) void gemm_kernel(
    const _Float16* __restrict__ A, const _Float16* __restrict__ Bt,
    float* __restrict__ C) {
  __shared__ _Float16 lds[2][4][8192];  // 128 KiB

  const int tid = threadIdx.x;
  const int lane = tid & 63;
  const int wave = tid >> 6;
  const int wm = wave >> 2;  // 0..1
  const int wn = wave & 3;   // 0..3

  // XCD-aware swizzle (T1), bn-fastest (round-4 proven)
  const int bid = blockIdx.x;
  const int g = (bid & 7) * 86 + (bid >> 3);
  const int bm = g / NBN;
  const int bn = g - bm * NBN;
  const size_t row0 = (size_t)bm * BM;
  const size_t col0 = (size_t)bn * BN;

  // staging addressing (T2 pre-swizzled source)
  const int sr = tid >> 2;
  const int pcb = (tid & 3) * 16;
  const int cb = pcb ^ (((sr >> 1) & 3) << 4);
  const _Float16* gA = A + (row0 + sr) * (size_t)K_DIM + cb / 2;
  const _Float16* gB = Bt + (col0 + sr) * (size_t)K_DIM + cb / 2;

  // fragment read addressing (16x16x32: row=lane&15, kgrp=lane>>4)
  const int frow = lane & 15;
  const int fpcb = 16 * ((lane >> 4) ^ ((lane >> 1) & 3));
  const int aoff = (wm * 128 + frow) * 32 + fpcb / 2;
  const int boff = (wn * 64 + frow) * 32 + fpcb / 2;

  f32x4 acc[8][4];
#pragma unroll
  for (int m = 0; m < 8; ++m)
#pragma unroll
    for (int n = 0; n < 4; ++n) acc[m][n] = (f32x4)0.0f;

  f16x8 aX[4], aY[4], bX[4], bY[4];

  // prologue: stage tile 0 into buf 0
  STAGE(0, 0, gA);
  STAGE(0, 2, gB);
  STAGE(0, 1, gA + 32);
  STAGE(0, 3, gB + 32);

  for (int t = 0; t < NT - 1; ++t) {
    const int cur = t & 1;
    const int nxt = cur ^ 1;
    const _Float16* gAn = gA + (size_t)(t + 1) * BK;
    const _Float16* gBn = gB + (size_t)(t + 1) * BK;
    TILE_BODY(cur, {
      STAGE(nxt, 0, gAn);
      STAGE(nxt, 2, gBn);
      STAGE(nxt, 1, gAn + 32);
      STAGE(nxt, 3, gBn + 32);
    });
  }
  // tail tile NT-1 in buf 1, no staging
  TILE_BODY(1, {});

  // epilogue: C/D layout col=lane&15, row=(lane>>4)*4+r
  const int crow = (lane >> 4) * 4;
  const int ccol = lane & 15;
  float* Cw = C + (row0 + wm * 128 + crow) * (size_t)N_DIM + col0 + wn * 64 + ccol;
#pragma unroll
  for (int m = 0; m < 8; ++m)
#pragma unroll
    for (int n = 0; n < 4; ++n)
#pragma unroll
      for (int r = 0; r < 4; ++r)
        Cw[(size_t)(m * 16 + r) * N_DIM + n * 16] = acc[m][n][r];
}

// ---------------------------------------------------------------------------
extern "C" void kernel_launch(void* const* d_in, const int* in_sizes, int n_in,
                              void* d_out, int out_size, void* d_ws, size_t ws_size,
                              hipStream_t stream) {
  const float* x = (const float*)d_in[0];
  const int* Wmag = (const int*)d_in[1];
  const int* Wsgn = (const int*)d_in[2];
  const float* scales = (const float*)d_in[3];
  const float* alphas = (const float*)d_in[4];
  const float* powers = (const float*)d_in[5];
  const float* divisors = (const float*)d_in[6];
  float* out = (float*)d_out;

  _Float16* xh = (_Float16*)d_ws;                        // 32 MB
  _Float16* Wh = xh + (size_t)M_DIM * K_DIM;             // 90 MB

  {
    int nthreads_total = (N_DIM * K_DIM) / 8;
    dequant_kernel<<<nthreads_total / 256, 256, 0, stream>>>(
        Wmag, Wsgn, scales, alphas, powers, divisors, Wh);
  }
  {
    int nthreads_total = (M_DIM * K_DIM) / 8;
    xconv_kernel<<<nthreads_total / 256, 256, 0, stream>>>(x, xh);
  }
  {
    dim3 grid(NBM * NBN);  // 688
    gemm_kernel<<<grid, 512, 0, stream>>>(xh, Wh, out);
  }
}

// Round 9
// 486.005 us; speedup vs baseline: 1.3274x; 1.2106x over previous
//
#include <hip/hip_runtime.h>
#include <hip/hip_bf16.h>
#include <hip/hip_fp16.h>

// Problem constants (reference: OUT=11008, IN=4096, B=2, S=2048)
#define K_DIM 4096
#define N_DIM 11008
#define M_DIM 4096  // B*S

typedef _Float16 f16x8 __attribute__((ext_vector_type(8)));
typedef float f32x4 __attribute__((ext_vector_type(4)));

typedef const __attribute__((address_space(1))) void* gas_cptr;
typedef __attribute__((address_space(3))) void* las_ptr;

__device__ __forceinline__ void gload_lds16(const void* g, void* l) {
  __builtin_amdgcn_global_load_lds((gas_cptr)g, (las_ptr)l, 16, 0, 0);
}

// ---------------------------------------------------------------------------
// Dequant via per-row LUT: mag is an INTEGER in [0,255], so the row's curve
// scale*(alpha*xn + (1-alpha)*xn^p), xn=m/divisor, has only 256 values.
// One block per row: 256 threads each compute one LUT entry (256 powf/row
// instead of 4096 -> 16x fewer transcendentals; kernel becomes memory-bound),
// then gather 16 elements/thread through LDS.
// ---------------------------------------------------------------------------
__global__ __launch_bounds__(256) void dequant_kernel(
    const int* __restrict__ mag, const int* __restrict__ sgn,
    const float* __restrict__ scales, const float* __restrict__ alphas,
    const float* __restrict__ powers, const float* __restrict__ divisors,
    _Float16* __restrict__ Wh) {
  __shared__ float tbl[256];
  const int o = blockIdx.x;   // row
  const int t = threadIdx.x;
  {
    float sc = scales[o];
    float al = alphas[o];
    float p = powers[o];
    float idv = 1.0f / divisors[o];
    float xn = (float)t * idv;
    float pw = __powf(xn, p);  // t==0 -> 0
    tbl[t] = sc * (al * xn + (1.0f - al) * pw);
  }
  __syncthreads();

  const size_t base = (size_t)o * K_DIM + (size_t)t * 16;
  const int4* mp = (const int4*)(mag + base);
  const int4* sp = (const int4*)(sgn + base);
  int4 m0 = mp[0], m1 = mp[1], m2 = mp[2], m3 = mp[3];
  int4 s0 = sp[0], s1 = sp[1], s2 = sp[2], s3 = sp[3];

  int mi[16] = {m0.x, m0.y, m0.z, m0.w, m1.x, m1.y, m1.z, m1.w,
                m2.x, m2.y, m2.z, m2.w, m3.x, m3.y, m3.z, m3.w};
  int si[16] = {s0.x, s0.y, s0.z, s0.w, s1.x, s1.y, s1.z, s1.w,
                s2.x, s2.y, s2.z, s2.w, s3.x, s3.y, s3.z, s3.w};

  f16x8 oa, ob;
#pragma unroll
  for (int e = 0; e < 8; ++e) oa[e] = (_Float16)((float)si[e] * tbl[mi[e]]);
#pragma unroll
  for (int e = 0; e < 8; ++e) ob[e] = (_Float16)((float)si[8 + e] * tbl[mi[8 + e]]);
  *(f16x8*)&Wh[base] = oa;
  *(f16x8*)&Wh[base + 8] = ob;
}

// ---------------------------------------------------------------------------
// x (fp32) -> fp16
// ---------------------------------------------------------------------------
__global__ __launch_bounds__(256) void xconv_kernel(const float* __restrict__ x,
                                                    _Float16* __restrict__ xh) {
  int v = blockIdx.x * 256 + threadIdx.x;
  int base = v * 8;
  float4 a = *(const float4*)(x + base);
  float4 b = *(const float4*)(x + base + 4);
  f16x8 o;
  o[0] = (_Float16)a.x; o[1] = (_Float16)a.y;
  o[2] = (_Float16)a.z; o[3] = (_Float16)a.w;
  o[4] = (_Float16)b.x; o[5] = (_Float16)b.y;
  o[6] = (_Float16)b.z; o[7] = (_Float16)b.w;
  *(f16x8*)&xh[base] = o;
}

// ---------------------------------------------------------------------------
// 256x256 GEMM_BT, BK=64, 512 thr = 8 waves (2x4), 16x16x32 f16 MFMA.
// Round-8 structure (1 barrier + 1 vmcnt per K-tile, register-pipelined
// phases) + T19 sched_group_barrier: each phase's ds_reads are interleaved
// INTO the 16-MFMA burst ({2 MFMA,1 DS}x8 / {4 MFMA,1 DS}x4) so the MFMA
// pipe keeps issuing while the other wave's reads drain (round-8 diagnosis:
// burst-read-then-burst-MFMA leaves both waves waiting simultaneously).
// lgkmcnt(0) at phase boundaries: the waited reads were issued a full MFMA
// burst (~310cy) earlier.  Swizzle (T2, 0 conflicts r4/r6/r8):
// colbyte ^= ((row>>1)&3)<<4.
// ---------------------------------------------------------------------------
#define BM 256
#define BN 256
#define BK 64
#define NT (K_DIM / BK)   // 64
#define NBN (N_DIM / BN)  // 43
#define NBM (M_DIM / BM)  // 16

#define BAR() __builtin_amdgcn_s_barrier()
#define LGKM0()                                              \
  asm volatile("s_waitcnt lgkmcnt(0)" ::: "memory");         \
  __builtin_amdgcn_sched_barrier(0)
#define VMC(N) asm volatile("s_waitcnt vmcnt(" #N ")" ::: "memory")
#define PRIO1() __builtin_amdgcn_s_setprio(1)
#define PRIO0() __builtin_amdgcn_s_setprio(0)
#define SGB(mask_, n_) __builtin_amdgcn_sched_group_barrier(mask_, n_, 0)

// interleave: 16 MFMA with 4 or 8 DS_READ (MFMA=0x8, DS_READ=0x100)
#define ILV4()                                   \
  do {                                           \
    SGB(0x8, 4); SGB(0x100, 1);                  \
    SGB(0x8, 4); SGB(0x100, 1);                  \
    SGB(0x8, 4); SGB(0x100, 1);                  \
    SGB(0x8, 4); SGB(0x100, 1);                  \
  } while (0)
#define ILV8()                                   \
  do {                                           \
    SGB(0x8, 2); SGB(0x100, 1);                  \
    SGB(0x8, 2); SGB(0x100, 1);                  \
    SGB(0x8, 2); SGB(0x100, 1);                  \
    SGB(0x8, 2); SGB(0x100, 1);                  \
    SGB(0x8, 2); SGB(0x100, 1);                  \
    SGB(0x8, 2); SGB(0x100, 1);                  \
    SGB(0x8, 2); SGB(0x100, 1);                  \
    SGB(0x8, 2); SGB(0x100, 1);                  \
  } while (0)

#define STAGE(buf_, reg_, gbase_)                                        \
  do {                                                                   \
    gload_lds16((gbase_), &lds[buf_][reg_][wave * 512]);                 \
    gload_lds16((gbase_) + 128 * (size_t)K_DIM,                          \
                &lds[buf_][reg_][4096 + wave * 512]);                    \
  } while (0)

#define RD_A(dst_, buf_, kh_, qm_)                                       \
  _Pragma("unroll") for (int m = 0; m < 4; ++m)                          \
      dst_[m] = *(const f16x8*)&lds[buf_][kh_][aoff + ((qm_)*4 + m) * 512];

#define RD_B(dst_, buf_, kh_)                                            \
  _Pragma("unroll") for (int n = 0; n < 4; ++n)                          \
      dst_[n] = *(const f16x8*)&lds[buf_][2 + (kh_)][boff + n * 512];

#define MFMA16(a_, b_, qm_)                                              \
  _Pragma("unroll") for (int i = 0; i < 4; ++i)                          \
      _Pragma("unroll") for (int j = 0; j < 4; ++j)                      \
          acc[(qm_)*4 + i][j] = __builtin_amdgcn_mfma_f32_16x16x32_f16(  \
              a_[i], b_[j], acc[(qm_)*4 + i][j], 0, 0, 0);

// One K-tile, 4 phases; each phase issues the NEXT phase's ds_reads
// interleaved into its MFMA burst via SGB.
#define TILE_BODY(buf_, DO_STAGE_)                                       \
  do {                                                                   \
    VMC(0);                                                              \
    BAR();                                                               \
    DO_STAGE_;                                                           \
    RD_A(aX, buf_, 0, 0);                                                \
    RD_B(bX, buf_, 0);                                                   \
    LGKM0();                                                             \
    /* ph1: mfma(aX,bX,q0) || read aY (kh0,q1) */                        \
    PRIO1();                                                             \
    RD_A(aY, buf_, 0, 1);                                                \
    MFMA16(aX, bX, 0);                                                   \
    ILV4();                                                              \
    PRIO0();                                                             \
    LGKM0();                                                             \
    /* ph2: mfma(aY,bX,q1) || read aX (kh1,q0), bY (kh1) */              \
    PRIO1();                                                             \
    RD_A(aX, buf_, 1, 0);                                                \
    RD_B(bY, buf_, 1);                                                   \
    MFMA16(aY, bX, 1);                                                   \
    ILV8();                                                              \
    PRIO0();                                                             \
    LGKM0();                                                             \
    /* ph3: mfma(aX,bY,q0) || read aY (kh1,q1) */                        \
    PRIO1();                                                             \
    RD_A(aY, buf_, 1, 1);                                                \
    MFMA16(aX, bY, 0);                                                   \
    ILV4();                                                              \
    PRIO0();                                                             \
    LGKM0();                                                             \
    /* ph4: mfma(aY,bY,q1) */                                            \
    PRIO1();                                                             \
    MFMA16(aY, bY, 1);                                                   \
    PRIO0();                                                             \
  } while (0)

__global__ __launch_bounds__(512, 2) void gemm_kernel(
    const _Float16* __restrict__ A, const _Float16* __restrict__ Bt,
    float* __restrict__ C) {
  __shared__ _Float16 lds[2][4][8192];  // 128 KiB

  const int tid = threadIdx.x;
  const int lane = tid & 63;
  const int wave = tid >> 6;
  const int wm = wave >> 2;  // 0..1
  const int wn = wave & 3;   // 0..3

  // XCD-aware swizzle (T1), bn-fastest (round-4 proven)
  const int bid = blockIdx.x;
  const int g = (bid & 7) * 86 + (bid >> 3);
  const int bm = g / NBN;
  const int bn = g - bm * NBN;
  const size_t row0 = (size_t)bm * BM;
  const size_t col0 = (size_t)bn * BN;

  // staging addressing (T2 pre-swizzled source)
  const int sr = tid >> 2;
  const int pcb = (tid & 3) * 16;
  const int cb = pcb ^ (((sr >> 1) & 3) << 4);
  const _Float16* gA = A + (row0 + sr) * (size_t)K_DIM + cb / 2;
  const _Float16* gB = Bt + (col0 + sr) * (size_t)K_DIM + cb / 2;

  // fragment read addressing (16x16x32: row=lane&15, kgrp=lane>>4)
  const int frow = lane & 15;
  const int fpcb = 16 * ((lane >> 4) ^ ((lane >> 1) & 3));
  const int aoff = (wm * 128 + frow) * 32 + fpcb / 2;
  const int boff = (wn * 64 + frow) * 32 + fpcb / 2;

  f32x4 acc[8][4];
#pragma unroll
  for (int m = 0; m < 8; ++m)
#pragma unroll
    for (int n = 0; n < 4; ++n) acc[m][n] = (f32x4)0.0f;

  f16x8 aX[4], aY[4], bX[4], bY[4];

  // prologue: stage tile 0 into buf 0
  STAGE(0, 0, gA);
  STAGE(0, 2, gB);
  STAGE(0, 1, gA + 32);
  STAGE(0, 3, gB + 32);

  for (int t = 0; t < NT - 1; ++t) {
    const int cur = t & 1;
    const int nxt = cur ^ 1;
    const _Float16* gAn = gA + (size_t)(t + 1) * BK;
    const _Float16* gBn = gB + (size_t)(t + 1) * BK;
    TILE_BODY(cur, {
      STAGE(nxt, 0, gAn);
      STAGE(nxt, 2, gBn);
      STAGE(nxt, 1, gAn + 32);
      STAGE(nxt, 3, gBn + 32);
    });
  }
  // tail tile NT-1 in buf 1, no staging
  TILE_BODY(1, {});

  // epilogue: C/D layout col=lane&15, row=(lane>>4)*4+r
  const int crow = (lane >> 4) * 4;
  const int ccol = lane & 15;
  float* Cw = C + (row0 + wm * 128 + crow) * (size_t)N_DIM + col0 + wn * 64 + ccol;
#pragma unroll
  for (int m = 0; m < 8; ++m)
#pragma unroll
    for (int n = 0; n < 4; ++n)
#pragma unroll
      for (int r = 0; r < 4; ++r)
        Cw[(size_t)(m * 16 + r) * N_DIM + n * 16] = acc[m][n][r];
}

// ---------------------------------------------------------------------------
extern "C" void kernel_launch(void* const* d_in, const int* in_sizes, int n_in,
                              void* d_out, int out_size, void* d_ws, size_t ws_size,
                              hipStream_t stream) {
  const float* x = (const float*)d_in[0];
  const int* Wmag = (const int*)d_in[1];
  const int* Wsgn = (const int*)d_in[2];
  const float* scales = (const float*)d_in[3];
  const float* alphas = (const float*)d_in[4];
  const float* powers = (const float*)d_in[5];
  const float* divisors = (const float*)d_in[6];
  float* out = (float*)d_out;

  _Float16* xh = (_Float16*)d_ws;                        // 32 MB
  _Float16* Wh = xh + (size_t)M_DIM * K_DIM;             // 90 MB

  // 1) dequantize W -> fp16 [N][K]  (per-row LUT, one block per row)
  dequant_kernel<<<N_DIM, 256, 0, stream>>>(
      Wmag, Wsgn, scales, alphas, powers, divisors, Wh);
  // 2) x -> fp16 [M][K]
  {
    int nthreads_total = (M_DIM * K_DIM) / 8;
    xconv_kernel<<<nthreads_total / 256, 256, 0, stream>>>(x, xh);
  }
  // 3) GEMM: [M][K] x [N][K]^T -> [M][N] f32
  {
    dim3 grid(NBM * NBN);  // 688
    gemm_kernel<<<grid, 512, 0, stream>>>(xh, Wh, out);
  }
}